// Round 13
// baseline (1819.871 us; speedup 1.0000x reference)
//
#include <hip/hip_runtime.h>
#include <hip/hip_bf16.h>

typedef __attribute__((ext_vector_type(8))) __bf16 bf16x8;
typedef __attribute__((ext_vector_type(4))) float f32x4;
typedef __attribute__((ext_vector_type(16))) float f32x16;
typedef __hip_bfloat16 bf16_t;

#define BB 8192L
#define HH 2048L
#define BH (8192L*2048L)      // elements per full [B,H] slab
#define WUNIT (2048L*2048L)   // elements per HxH weight unit
#define WT (3L*2048L*2048L)   // elements per [3,H,H] weight tensor
#define LDS_TOTAL 163840      // A 3x32KB triple-buffer + B 2x32KB double-buffer

struct SlabMap { int a[16]; int w[16]; };
struct Ptrs4 { const float* in[4]; bf16_t* out[4]; };
struct FoldJob { const float* W2; const float* b1; const float* badd; float* out; int ld; };
struct FoldPack { FoldJob j[16]; };
struct GJob { const bf16_t* A; const bf16_t* Bw; bf16_t* C; int lda; int ldc; };
struct GJobs { GJob j[18]; };

__device__ __forceinline__ void gload_lds16(const void* g, void* l) {
    __builtin_amdgcn_global_load_lds((__attribute__((address_space(1))) void*)g,
                                     (__attribute__((address_space(3))) void*)l, 16, 0, 0);
}

// ============ 256x256 core, r7 schedule + 32x32x16 MFMA ==========================
// Schedule (best of 6 measured: r7=366us vs r8 414 / r9 391 / r10 FAIL / r11 394):
// per phase {stage; ds_read frags; s_barrier; sched_barrier; setprio; MFMA; setprio}.
// A triple-buffered (slot s%3), B double-buffered (slot s&1); boundary vmcnt(8)
// keeps K-tile s+2's 8 loads in flight; tail vmcnt(0). Spill-free REQUIRED
// (r10: scratch ops increment vmcnt and corrupt the hand count).
// MFMA = v_mfma_f32_32x32x16_bf16 (4061 FLOP/cy vs 16x16's 3562, m119): 32 MFMA
// per K-tile/wave instead of 64 -> less issue pressure, longer shadows.
// Frag layouts: A row=lane&31, k-octet=lane>>5 (khalf); B col=lane&31, same k.
// C/D: col=lane&31, row=(r&3)+8*(r>>2)+4*(lane>>5)  [m74/m101 verified].
// LDS rows [*][64] bf16, XOR swizzle 16B-chunk ^= row&7, source pre-swizzled
// (rule 21: global_load_lds writes linearly).
template<bool OUT_F32, bool FUSEK>
__device__ __forceinline__ void gemm_core(
    const bf16_t* __restrict__ A, int lda, long aslab,
    const bf16_t* __restrict__ Wb, int ldb,
    const float* __restrict__ be,
    void* __restrict__ Cout, int ldc,
    long rowA0, long rowB0, int K, char* lds)
{
    const int tid  = threadIdx.x;
    const int lane = tid & 63;
    const int w    = tid >> 6;
    const int wm   = w >> 2, wn = w & 3;   // 2M x 4N waves, wave tile 128x64

    const int srow    = tid >> 3;                       // 0..63
    const int schunk8 = ((tid & 7) ^ (srow & 7)) * 8;   // pre-swizzled src k-offset
    const int wuni    = w * 1024;                       // wave-uniform LDS base
    const int NK = K >> 6;

    auto stageA = [&](int s) {            // all 4 A quarters of K-tile s
        char* dst = lds + (s % 3) * 32768;
        const int k0 = s << 6;
        const bf16_t* Aeff; int ka;
        if constexpr (FUSEK) { Aeff = A + (long)(k0 >> 11) * aslab; ka = k0 & 2047; }
        else                 { Aeff = A; ka = k0; }
        #pragma unroll
        for (int i = 0; i < 4; ++i)
            gload_lds16(Aeff + (rowA0 + i*64 + srow) * (long)lda + (ka + schunk8), dst + i*8192 + wuni);
    };
    auto stageB = [&](int s, int q) {     // one B quarter (2 loads)
        char* dst = lds + 98304 + (s & 1) * 32768 + q*16384;
        const int k0 = s << 6;
        #pragma unroll
        for (int j = 0; j < 2; ++j)
            gload_lds16(Wb + (rowB0 + q*128 + j*64 + srow) * (long)ldb + (k0 + schunk8), dst + j*8192 + wuni);
    };

    f32x16 acc[4][2];   // [row-tile rt][col-tile ct], each 32x32
    #pragma unroll
    for (int i = 0; i < 4; ++i)
        #pragma unroll
        for (int j = 0; j < 2; ++j)
            #pragma unroll
            for (int r = 0; r < 16; ++r) acc[i][j][r] = 0.f;

    stageA(0); stageB(0,0); stageB(0,1);
    stageA(1); stageB(1,0); stageB(1,1);
    asm volatile("s_waitcnt vmcnt(8)" ::: "memory");
    asm volatile("s_barrier" ::: "memory");

    const int khalf  = lane >> 5;               // k-octet select
    const int arow32 = wm*128 + (lane & 31);    // + rt*32
    const int brow32 = wn*64  + (lane & 31);    // + ct*32

    // ks = K16-subtile (0..3); 16B chunk index = ks*2 + khalf, XOR row&7 swizzle
    #define LDSA(row, ks) (*(const bf16x8*)(bufA + (row)*128 + (((((ks)*2) + khalf) ^ ((row) & 7)) * 16)))
    #define LDSB(row, ks) (*(const bf16x8*)(bufB + (row)*128 + (((((ks)*2) + khalf) ^ ((row) & 7)) * 16)))

    for (int s = 0; s < NK; ++s) {
        char* bufA = lds + (s % 3) * 32768;
        char* bufB = lds + 98304 + (s & 1) * 32768;
        bf16x8 a[2][4], b0[4], b1[4];

        // ---- ph0: rt{0,1} x ct0 ----
        if (s + 2 < NK) stageA(s + 2);
        #pragma unroll
        for (int ks = 0; ks < 4; ++ks) b0[ks] = LDSB(brow32, ks);
        #pragma unroll
        for (int i = 0; i < 2; ++i)
            #pragma unroll
            for (int ks = 0; ks < 4; ++ks) a[i][ks] = LDSA(arow32 + i*32, ks);
        asm volatile("s_barrier" ::: "memory");
        __builtin_amdgcn_sched_barrier(0);
        __builtin_amdgcn_s_setprio(1);
        #pragma unroll
        for (int ks = 0; ks < 4; ++ks) {
            acc[0][0] = __builtin_amdgcn_mfma_f32_32x32x16_bf16(a[0][ks], b0[ks], acc[0][0], 0, 0, 0);
            acc[1][0] = __builtin_amdgcn_mfma_f32_32x32x16_bf16(a[1][ks], b0[ks], acc[1][0], 0, 0, 0);
        }
        __builtin_amdgcn_s_setprio(0);

        // ---- ph1: rt{0,1} x ct1 ----
        #pragma unroll
        for (int ks = 0; ks < 4; ++ks) b1[ks] = LDSB(brow32 + 32, ks);
        asm volatile("s_barrier" ::: "memory");
        __builtin_amdgcn_sched_barrier(0);
        __builtin_amdgcn_s_setprio(1);
        #pragma unroll
        for (int ks = 0; ks < 4; ++ks) {
            acc[0][1] = __builtin_amdgcn_mfma_f32_32x32x16_bf16(a[0][ks], b1[ks], acc[0][1], 0, 0, 0);
            acc[1][1] = __builtin_amdgcn_mfma_f32_32x32x16_bf16(a[1][ks], b1[ks], acc[1][1], 0, 0, 0);
        }
        __builtin_amdgcn_s_setprio(0);

        // ---- ph2: rt{2,3} x ct0 ----
        if (s + 2 < NK) stageB(s + 2, 0);
        #pragma unroll
        for (int i = 0; i < 2; ++i)
            #pragma unroll
            for (int ks = 0; ks < 4; ++ks) a[i][ks] = LDSA(arow32 + 64 + i*32, ks);
        asm volatile("s_barrier" ::: "memory");
        __builtin_amdgcn_sched_barrier(0);
        __builtin_amdgcn_s_setprio(1);
        #pragma unroll
        for (int ks = 0; ks < 4; ++ks) {
            acc[2][0] = __builtin_amdgcn_mfma_f32_32x32x16_bf16(a[0][ks], b0[ks], acc[2][0], 0, 0, 0);
            acc[3][0] = __builtin_amdgcn_mfma_f32_32x32x16_bf16(a[1][ks], b0[ks], acc[3][0], 0, 0, 0);
        }
        __builtin_amdgcn_s_setprio(0);

        // ---- ph3: rt{2,3} x ct1 ----
        if (s + 2 < NK) stageB(s + 2, 1);
        if (s + 1 < NK) {
            if (s + 2 < NK) asm volatile("s_waitcnt vmcnt(8)" ::: "memory");
            else            asm volatile("s_waitcnt vmcnt(0)" ::: "memory");
            asm volatile("s_barrier" ::: "memory");
            __builtin_amdgcn_sched_barrier(0);
        }
        __builtin_amdgcn_s_setprio(1);
        #pragma unroll
        for (int ks = 0; ks < 4; ++ks) {
            acc[2][1] = __builtin_amdgcn_mfma_f32_32x32x16_bf16(a[0][ks], b1[ks], acc[2][1], 0, 0, 0);
            acc[3][1] = __builtin_amdgcn_mfma_f32_32x32x16_bf16(a[1][ks], b1[ks], acc[3][1], 0, 0, 0);
        }
        __builtin_amdgcn_s_setprio(0);
    }
    #undef LDSA
    #undef LDSB

    // C/D: col = lane&31, row = (r&3) + 8*(r>>2) + 4*khalf  [m74/m101]
    const long crow0 = rowA0 + wm*128 + 4*khalf;
    const int  ccol0 = (int)rowB0 + wn*64 + (lane & 31);
    #pragma unroll
    for (int rt = 0; rt < 4; ++rt) {
        #pragma unroll
        for (int ct = 0; ct < 2; ++ct) {
            const int col = ccol0 + ct*32;
            const float bv = be ? be[col] : 0.f;
            #pragma unroll
            for (int r = 0; r < 16; ++r) {
                const long row = crow0 + rt*32 + (r & 3) + 8*(r >> 2);
                const float val = acc[rt][ct][r] + bv;
                if constexpr (OUT_F32) ((float*)Cout)[row*(long)ldc + col] = val;
                else ((bf16_t*)Cout)[row*(long)ldc + col] = __float2bfloat16(val);
            }
        }
    }
}

template<bool OUT_F32, bool FUSEK>
__global__ __launch_bounds__(512, 1)
void gemm256(const bf16_t* __restrict__ A, int lda, long aslab, SlabMap map, int mshift,
             const bf16_t* __restrict__ Bw, int ldb,
             const float* __restrict__ bias,
             void* __restrict__ Cout, int ldc, long cslab, int K)
{
    extern __shared__ char lds[];
    const int nwg = (int)gridDim.x;
    const int wid = (int)blockIdx.x;
    const int swz = (wid & 7) * (nwg >> 3) + (wid >> 3);
    const int bx  = swz & 7;               // N=2048 -> 8 col-blocks
    const int by  = swz >> 3;

    const int  sl    = by >> mshift;
    const long rowA0 = (long)(by & ((1 << mshift) - 1)) * 256;
    const long rowB0 = (long)bx * 256;
    const bf16_t* Ab = FUSEK ? A : (A + (long)map.a[sl] * aslab);
    const bf16_t* Wb = Bw + (long)map.w[sl] * WUNIT;
    const float*  be = bias ? (bias + (long)map.w[sl] * HH) : nullptr;
    const long cbase = (long)sl * cslab;
    void* Cj = OUT_F32 ? (void*)((float*)Cout + cbase) : (void*)((bf16_t*)Cout + cbase);
    gemm_core<OUT_F32, FUSEK>(Ab, lda, aslab, Wb, ldb, be, Cj, ldc, rowA0, rowB0, K, lds);
}

// all 18 weight-fold GEMMs (M=N=K=2048 each) in one dispatch: 18 jobs x 64 blocks
__global__ __launch_bounds__(512, 1)
void gemm_fold(GJobs js)
{
    extern __shared__ char lds[];
    const int nwg = (int)gridDim.x;     // 1152, multiple of 8
    const int wid = (int)blockIdx.x;
    const int swz = (wid & 7) * (nwg >> 3) + (wid >> 3);
    const GJob jb = js.j[swz >> 6];
    const int inner = swz & 63;
    const long rowA0 = (long)(inner >> 3) * 256;
    const long rowB0 = (long)(inner & 7) * 256;
    gemm_core<false, false>(jb.A, jb.lda, 0L, jb.Bw, 2048, nullptr,
                            (void*)jb.C, jb.ldc, rowA0, rowB0, 2048, lds);
}

__global__ __launch_bounds__(256)
void f2b_kernel(const float* __restrict__ in, bf16_t* __restrict__ out, long n)
{
    long i = ((long)blockIdx.x * 256 + threadIdx.x) * 4;
    const long stride = (long)gridDim.x * 256 * 4;
    for (; i < n; i += stride) {
        const float4 v = *(const float4*)(in + i);
        __hip_bfloat162 lo, hi;
        lo.x = __float2bfloat16(v.x); lo.y = __float2bfloat16(v.y);
        hi.x = __float2bfloat16(v.z); hi.y = __float2bfloat16(v.w);
        *(__hip_bfloat162*)(out + i)     = lo;
        *(__hip_bfloat162*)(out + i + 2) = hi;
    }
}

// batched f2b over 4 equal-size [3,2048,2048] tensors
__global__ __launch_bounds__(256)
void f2b4_kernel(Ptrs4 p)
{
    const long total = 4 * WT;
    long i = ((long)blockIdx.x * 256 + threadIdx.x) * 4;
    const long stride = (long)gridDim.x * 256 * 4;
    for (; i < total; i += stride) {
        const int  t   = (int)(i / WT);
        const long off = i - (long)t * WT;
        const float4 v = *(const float4*)(p.in[t] + off);
        __hip_bfloat162 lo, hi;
        lo.x = __float2bfloat16(v.x); lo.y = __float2bfloat16(v.y);
        hi.x = __float2bfloat16(v.z); hi.y = __float2bfloat16(v.w);
        *(__hip_bfloat162*)(p.out[t] + off)     = lo;
        *(__hip_bfloat162*)(p.out[t] + off + 2) = hi;
    }
}

// batched transpose-convert: out[mat][c][r] = (bf16) in[mat][r][c], 4 tensors x 3 mats
__global__ __launch_bounds__(256)
void f2bT4_kernel(Ptrs4 p)
{
    __shared__ float sm[64][65];
    const int gmat = blockIdx.x >> 10;       // 0..11
    const int t    = gmat / 3, m = gmat % 3;
    const int tile = blockIdx.x & 1023;
    const int tr   = tile >> 5, tc = tile & 31;
    const int lr = threadIdx.x >> 4;
    const int lc = (threadIdx.x & 15) * 4;
    const float* src = p.in[t] + (long)m*WUNIT + ((long)tr*64)*2048 + tc*64;
    #pragma unroll
    for (int it = 0; it < 4; ++it) {
        const int r = lr + it*16;
        const float4 v = *(const float4*)(src + (long)r*2048 + lc);
        sm[r][lc] = v.x; sm[r][lc+1] = v.y; sm[r][lc+2] = v.z; sm[r][lc+3] = v.w;
    }
    __syncthreads();
    bf16_t* dst = p.out[t] + (long)m*WUNIT + ((long)tc*64)*2048 + tr*64;
    #pragma unroll
    for (int it = 0; it < 4; ++it) {
        const int r = lr + it*16;
        __hip_bfloat162 p0, p1;
        p0.x = __float2bfloat16(sm[lc+0][r]); p0.y = __float2bfloat16(sm[lc+1][r]);
        p1.x = __float2bfloat16(sm[lc+2][r]); p1.y = __float2bfloat16(sm[lc+3][r]);
        *(__hip_bfloat162*)(dst + (long)r*2048 + lc)     = p0;
        *(__hip_bfloat162*)(dst + (long)r*2048 + lc + 2) = p1;
    }
}

// all 16 bias folds in one dispatch: out[g2] = sum_k W2[g2*ld+k]*b1[k] + badd[g2]
__global__ __launch_bounds__(256)
void biasfold_all(FoldPack p)
{
    const FoldJob jb = p.j[blockIdx.x >> 11];
    const int g2 = blockIdx.x & 2047;
    const int t  = threadIdx.x;
    float s = 0.f;
    for (int k = t; k < jb.ld; k += 256) s += jb.W2[(long)g2*jb.ld + k] * jb.b1[k];
    #pragma unroll
    for (int off = 32; off > 0; off >>= 1) s += __shfl_xor(s, off);
    __shared__ float rs[4];
    if ((t & 63) == 0) rs[t >> 6] = s;
    __syncthreads();
    if (t == 0) jb.out[g2] = rs[0] + rs[1] + rs[2] + rs[3] + jb.badd[g2];
}

// one wave per (v, b, head): q_len=1 attention over the 2 other views.
__global__ __launch_bounds__(256)
void attn_kernel(const bf16_t* __restrict__ q2, const bf16_t* __restrict__ k2,
                 const bf16_t* __restrict__ v2, bf16_t* __restrict__ ctx, int bshift)
{
    const long gw = (long)blockIdx.x * 4 + (threadIdx.x >> 6);
    const int lane = threadIdx.x & 63;
    const int  v_  = (int)(gw >> (bshift + 4));
    const long rem = gw & ((1L << (bshift + 4)) - 1);
    const long b   = rem >> 4;
    const int  n   = (int)(rem & 15);
    const long base = ((((long)v_ << bshift) + b)) * HH + (long)n * 128 + lane * 2;

    const __hip_bfloat162 qv = *(const __hip_bfloat162*)(q2 + base);
    const float q0 = __bfloat162float(qv.x), q1 = __bfloat162float(qv.y);
    float s[2], va[2], vb[2];
    #pragma unroll
    for (int j = 0; j < 2; ++j) {
        const long kb = ((((long)(v_*2 + j) << bshift) + b)) * HH + (long)n * 128 + lane * 2;
        const __hip_bfloat162 kv = *(const __hip_bfloat162*)(k2 + kb);
        float p = q0 * __bfloat162float(kv.x) + q1 * __bfloat162float(kv.y);
        #pragma unroll
        for (int off = 32; off > 0; off >>= 1) p += __shfl_xor(p, off);
        s[j] = p;
        const __hip_bfloat162 vv = *(const __hip_bfloat162*)(v2 + kb);
        va[j] = __bfloat162float(vv.x); vb[j] = __bfloat162float(vv.y);
    }
    const float scale = 0.08838834764831845f; // 1/sqrt(128)
    const float s0 = s[0] * scale, s1 = s[1] * scale;
    const float m  = fmaxf(s0, s1);
    const float e0 = expf(s0 - m), e1 = expf(s1 - m);
    const float inv = 1.0f / (e0 + e1);
    const float a0 = e0 * inv, a1 = e1 * inv;
    __hip_bfloat162 o;
    o.x = __float2bfloat16(a0 * va[0] + a1 * va[1]);
    o.y = __float2bfloat16(a0 * vb[0] + a1 * vb[1]);
    *(__hip_bfloat162*)(ctx + base) = o;
}

// residual (views[0] chunk) + LayerNorm, one block per row
__global__ __launch_bounds__(256)
void ln_kernel(const float* __restrict__ proj, const float* __restrict__ v0,
               const float* __restrict__ gamma, const float* __restrict__ beta,
               float* __restrict__ out)
{
    const long b = blockIdx.x;
    const int t = threadIdx.x;
    const float* pr = proj + b * HH;
    const float* vw = v0 + b * HH;
    float x[8]; float s = 0.f, s2 = 0.f;
    #pragma unroll
    for (int k = 0; k < 8; ++k) {
        const int idx = t + k * 256;
        x[k] = vw[idx] + pr[idx];
        s += x[k]; s2 += x[k] * x[k];
    }
    #pragma unroll
    for (int off = 32; off > 0; off >>= 1) { s += __shfl_xor(s, off); s2 += __shfl_xor(s2, off); }
    __shared__ float rs[4], rs2[4];
    if ((t & 63) == 0) { rs[t >> 6] = s; rs2[t >> 6] = s2; }
    __syncthreads();
    s  = rs[0] + rs[1] + rs[2] + rs[3];
    s2 = rs2[0] + rs2[1] + rs2[2] + rs2[3];
    const float mu  = s * (1.0f / 2048.0f);
    const float var = s2 * (1.0f / 2048.0f) - mu * mu;
    const float rstd = rsqrtf(var + 1e-5f);
    #pragma unroll
    for (int k = 0; k < 8; ++k) {
        const int idx = t + k * 256;
        out[b * HH + idx] = (x[k] - mu) * rstd * gamma[idx] + beta[idx];
    }
}

extern "C" void kernel_launch(void* const* d_in, const int* in_sizes, int n_in,
                              void* d_out, int out_size, void* d_ws, size_t ws_size,
                              hipStream_t stream)
{
    const float* views = (const float*)d_in[0];
    const float* Wq   = (const float*)d_in[1];  const float* bq   = (const float*)d_in[2];
    const float* Wk   = (const float*)d_in[3];  const float* bk   = (const float*)d_in[4];
    const float* Wv   = (const float*)d_in[5];  const float* bv   = (const float*)d_in[6];
    const float* Wiq  = (const float*)d_in[7];  const float* biq  = (const float*)d_in[8];
    const float* Wik  = (const float*)d_in[9];  const float* bik  = (const float*)d_in[10];
    const float* Wiv  = (const float*)d_in[11]; const float* biv  = (const float*)d_in[12];
    const float* Wo   = (const float*)d_in[13]; const float* bo   = (const float*)d_in[14];
    const float* Wout = (const float*)d_in[15]; const float* bout = (const float*)d_in[16];
    const float* gamma= (const float*)d_in[17]; const float* beta = (const float*)d_in[18];

    static bool attr_set = false;
    if (!attr_set) {
        hipFuncSetAttribute((const void*)gemm256<false,false>,
                            hipFuncAttributeMaxDynamicSharedMemorySize, LDS_TOTAL);
        hipFuncSetAttribute((const void*)gemm256<true,true>,
                            hipFuncAttributeMaxDynamicSharedMemorySize, LDS_TOTAL);
        hipFuncSetAttribute((const void*)gemm_fold,
                            hipFuncAttributeMaxDynamicSharedMemorySize, LDS_TOTAL);
        attr_set = true;
    }

    // ---- workspace: persistent folded weights + overlaid {fold-scratch | activations} ----
    char* ws = (char*)d_ws;
    bf16_t* WQ2  = (bf16_t*)ws;                  // 3u folded q   (WQ2|WK2|WV2 contiguous
    bf16_t* WK2  = WQ2 + 3*WUNIT;                // 6u folded k    -> single QKV dispatch
    bf16_t* WV2  = WK2 + 6*WUNIT;                // 6u folded v    indexes WQ2 + w*WUNIT)
    bf16_t* WFIN = WV2 + 6*WUNIT;                // 3u folded final, [2048][6144]
    float*  BQ2  = (float*)(WFIN + 3*WUNIT);     // biases contiguous 3|6|6 likewise
    float*  BK2  = BQ2 + 3*HH;
    float*  BV2  = BK2 + 6*HH;
    float*  BFIN = BV2 + 6*HH;
    const long FIXED = 18L*WUNIT*2 + 16L*HH*4;   // 151,126,016 B

    char* R = ws + FIXED;
    bf16_t* WIQ   = (bf16_t*)R;
    bf16_t* WIK   = WIQ  + 3*WUNIT;
    bf16_t* WIV   = WIK  + 3*WUNIT;
    bf16_t* WOUTB = WIV  + 3*WUNIT;
    bf16_t* WQT   = WOUTB+ 3*WUNIT;
    bf16_t* WKT   = WQT  + 3*WUNIT;
    bf16_t* WVT   = WKT  + 3*WUNIT;
    bf16_t* WOT   = WVT  + 3*WUNIT;              // scratch total 24u = 201.3 MB

    const long scratch = 24L*WUNIT*2;
    long Bc = 8192;
    while (Bc > 256) {
        long need = Bc * 73728L; if (need < scratch) need = scratch;
        if (FIXED + need <= (long)ws_size) break;
        Bc >>= 1;
    }
    const int mshift = __builtin_ctzl((unsigned long)Bc) - 8;  // log2(Bc/256)
    const int bshift = __builtin_ctzl((unsigned long)Bc);      // log2(Bc)
    const long S1 = Bc * HH;

    bf16_t* VBF = (bf16_t*)R;            // views bf16 -> later ctx (3 slabs)
    bf16_t* Q2B = VBF + 3*S1;            // q2 (3)  | Q2B|K2|V2 contiguous (15 slabs)
    bf16_t* K2  = Q2B + 3*S1;            // k2 (6)
    bf16_t* V2  = K2  + 6*S1;            // v2 (6)
    float*  PROJ= (float*)K2;            // aliases K2 (dead after attn)

    // merged QKV map: slabs 0-2 q2, 3-8 k2 pairs, 9-14 v2 pairs
    const SlabMap mp15 = {{0,1,2, 1,2,0,2,0,1, 1,2,0,2,0,1},
                          {0,1,2, 3,4,5,6,7,8, 9,10,11,12,13,14}};
    const SlabMap mp1  = {{0},{0}};
    const int oth[3][2] = {{1,2},{0,2},{0,1}};

    // ---- one-time: weight conversions (2 batched dispatches) ----
    {
        Ptrs4 c1 = {{Wiq, Wik, Wiv, Wout}, {WIQ, WIK, WIV, WOUTB}};
        f2b4_kernel<<<8192, 256, 0, stream>>>(c1);
        Ptrs4 c2 = {{Wq, Wk, Wv, Wo}, {WQT, WKT, WVT, WOT}};
        f2bT4_kernel<<<12288, 256, 0, stream>>>(c2);
    }
    // ---- one-time: all 18 weight-fold GEMMs in ONE dispatch ----
    {
        GJobs js;
        for (int v = 0; v < 3; ++v)
            js.j[v] = { WIQ + (long)v*WUNIT, WQT + (long)v*WUNIT, WQ2 + (long)v*WUNIT, 2048, 2048 };
        for (int v = 0; v < 3; ++v)
            for (int j = 0; j < 2; ++j) {
                const int p = v*2 + j, o = oth[v][j];
                js.j[3 + p] = { WIK + (long)v*WUNIT, WKT + (long)o*WUNIT, WK2 + (long)p*WUNIT, 2048, 2048 };
                js.j[9 + p] = { WIV + (long)v*WUNIT, WVT + (long)o*WUNIT, WV2 + (long)p*WUNIT, 2048, 2048 };
            }
        for (int v = 0; v < 3; ++v)
            js.j[15 + v] = { WOUTB + (long)v*2048, WOT + (long)v*WUNIT, WFIN + (long)v*2048, 6144, 6144 };
        gemm_fold<<<1152, 512, LDS_TOTAL, stream>>>(js);
    }
    // ---- one-time: all 16 exact bias folds in one dispatch ----
    {
        FoldPack fp;
        for (int v = 0; v < 3; ++v)
            fp.j[v] = { Wiq + (long)v*WUNIT, bq + v*HH, biq + v*HH, BQ2 + v*HH, 2048 };
        for (int v = 0; v < 3; ++v)
            for (int j = 0; j < 2; ++j) {
                const int p = v*2 + j, o = oth[v][j];
                fp.j[3 + p] = { Wik + (long)v*WUNIT, bk + o*HH, bik + v*HH, BK2 + p*HH, 2048 };
                fp.j[9 + p] = { Wiv + (long)v*WUNIT, bv + o*HH, biv + v*HH, BV2 + p*HH, 2048 };
            }
        fp.j[15] = { Wout, bo, bout, BFIN, 6144 };
        biasfold_all<<<32768, 256, 0, stream>>>(fp);
    }

    const int nwg15 = 8 * 15 * (int)(Bc >> 8);
    const int nwg1  = 8 * 1 * (int)(Bc >> 8);
    const int vgrid = (int)((S1 / 1024 > 8192) ? 8192 : S1 / 1024);

    for (long b0 = 0; b0 < BB; b0 += Bc) {
        if (Bc == 8192) {
            f2b_kernel<<<8192, 256, 0, stream>>>(views, VBF, 3*BH);
        } else {
            for (int v = 0; v < 3; ++v)
                f2b_kernel<<<vgrid, 256, 0, stream>>>(views + v*BH + b0*HH, VBF + v*S1, S1);
        }
        // q2 + k2 + v2 in ONE 15-slab dispatch from folded weights
        gemm256<false,false><<<nwg15, 512, LDS_TOTAL, stream>>>(VBF, 2048, S1, mp15, mshift, WQ2, 2048, BQ2, (void*)Q2B, 2048, S1, 2048);
        // attention: ctx -> VBF (views_bf dead)
        attn_kernel<<<(int)(12*Bc), 256, 0, stream>>>(Q2B, K2, V2, VBF, bshift);
        // fused projection: proj = sum_v ctx[v] @ WFIN_v^T + BFIN (K=6144 over ctx slabs)
        gemm256<true,true><<<nwg1, 512, LDS_TOTAL, stream>>>(VBF, 2048, S1, mp1, mshift, WFIN, 6144, BFIN, (void*)PROJ, 2048, 0, 6144);
        // residual + LayerNorm
        ln_kernel<<<(int)Bc, 256, 0, stream>>>(PROJ, views + b0*HH, gamma, beta, ((float*)d_out) + b0*HH);
    }
}

// Round 14
// 1642.039 us; speedup vs baseline: 1.1083x; 1.1083x over previous
//
#include <hip/hip_runtime.h>
#include <hip/hip_bf16.h>

typedef __attribute__((ext_vector_type(8))) __bf16 bf16x8;
typedef __attribute__((ext_vector_type(4))) float f32x4;
typedef __hip_bfloat16 bf16_t;

#define BB 8192L
#define HH 2048L
#define BH (8192L*2048L)      // elements per full [B,H] slab
#define WUNIT (2048L*2048L)   // elements per HxH weight unit
#define WT (3L*2048L*2048L)   // elements per [3,H,H] weight tensor
#define LDS_TOTAL 163840      // A 3x32KB triple-buffer + B 2x32KB double-buffer

struct SlabMap { int a[16]; int w[16]; };
struct Ptrs4 { const float* in[4]; bf16_t* out[4]; };
struct FoldJob { const float* W2; const float* b1; const float* badd; float* out; int ld; };
struct FoldPack { FoldJob j[16]; };
struct GJob { const bf16_t* A; const bf16_t* Bw; bf16_t* C; int lda; int ldc; };
struct GJobs { GJob j[18]; };

__device__ __forceinline__ void gload_lds16(const void* g, void* l) {
    __builtin_amdgcn_global_load_lds((__attribute__((address_space(1))) void*)g,
                                     (__attribute__((address_space(3))) void*)l, 16, 0, 0);
}

// ============ round-7 8-phase 256x256 core, 16x16x32 MFMA (measured best) ========
// per phase {stage; ds_read frags; s_barrier; sched_barrier; setprio; MFMA; setprio}.
// A triple-buffered (slot s%3), B double-buffered (slot s&1); boundary vmcnt(8)
// keeps K-tile s+2's 8 loads in flight; tail vmcnt(0). Spill-free REQUIRED
// (r10: scratch ops increment vmcnt and corrupt the hand count).
// Schedule ledger: r8 lockstep 414us / r9 2-blk 391 / r11 drift 394 /
// r13 32x32-MFMA 1060 (4-way bank conflict: 32 rows over 8 chunk slots) --
// this r7 structure at 366us(6-slab) is the measured local optimum.
// 16x16 frag reads are conflict-free: 16 rows/lane-group over 8 XOR slots = 2-way (free, m136).
// LDS rows [*][64] bf16, XOR swizzle 16B-chunk ^= row&7, source pre-swizzled (rule 21).
template<bool OUT_F32, bool FUSEK>
__device__ __forceinline__ void gemm_core(
    const bf16_t* __restrict__ A, int lda, long aslab,
    const bf16_t* __restrict__ Wb, int ldb,
    const float* __restrict__ be,
    void* __restrict__ Cout, int ldc,
    long rowA0, long rowB0, int K, char* lds)
{
    const int tid  = threadIdx.x;
    const int lane = tid & 63;
    const int w    = tid >> 6;
    const int wm   = w >> 2, wn = w & 3;   // 2M x 4N waves

    const int srow    = tid >> 3;                       // 0..63
    const int schunk8 = ((tid & 7) ^ (srow & 7)) * 8;   // pre-swizzled src k-offset
    const int wuni    = w * 1024;                       // wave-uniform LDS base
    const int NK = K >> 6;

    auto stageA = [&](int s) {            // all 4 A quarters of K-tile s
        char* dst = lds + (s % 3) * 32768;
        const int k0 = s << 6;
        const bf16_t* Aeff; int ka;
        if constexpr (FUSEK) { Aeff = A + (long)(k0 >> 11) * aslab; ka = k0 & 2047; }
        else                 { Aeff = A; ka = k0; }
        #pragma unroll
        for (int i = 0; i < 4; ++i)
            gload_lds16(Aeff + (rowA0 + i*64 + srow) * (long)lda + (ka + schunk8), dst + i*8192 + wuni);
    };
    auto stageB = [&](int s, int q) {     // one B quarter (2 loads)
        char* dst = lds + 98304 + (s & 1) * 32768 + q*16384;
        const int k0 = s << 6;
        #pragma unroll
        for (int j = 0; j < 2; ++j)
            gload_lds16(Wb + (rowB0 + q*128 + j*64 + srow) * (long)ldb + (k0 + schunk8), dst + j*8192 + wuni);
    };

    f32x4 acc[8][4];
    const f32x4 zero = {0.f, 0.f, 0.f, 0.f};
    #pragma unroll
    for (int i = 0; i < 8; ++i)
        #pragma unroll
        for (int j = 0; j < 4; ++j) acc[i][j] = zero;

    stageA(0); stageB(0,0); stageB(0,1);
    stageA(1); stageB(1,0); stageB(1,1);
    asm volatile("s_waitcnt vmcnt(8)" ::: "memory");
    asm volatile("s_barrier" ::: "memory");

    const int arow16 = wm*128 + (lane & 15);
    const int brow16 = wn*64  + (lane & 15);
    const int kb     = (lane >> 4) * 16;

    #define LDSA(row, kh) (*(const bf16x8*)(bufA + (row)*128 + (((kh)*64 + kb) ^ (((row) & 7) << 4))))
    #define LDSB(row, kh) (*(const bf16x8*)(bufB + (row)*128 + (((kh)*64 + kb) ^ (((row) & 7) << 4))))

    for (int s = 0; s < NK; ++s) {
        char* bufA = lds + (s % 3) * 32768;
        char* bufB = lds + 98304 + (s & 1) * 32768;
        bf16x8 a[4][2], b0[2][2], b1[2][2];

        // ---- ph0: q0 x c0 ----
        if (s + 2 < NK) stageA(s + 2);
        #pragma unroll
        for (int cf = 0; cf < 2; ++cf) {
            const int r = brow16 + cf*16;
            #pragma unroll
            for (int kh = 0; kh < 2; ++kh) b0[cf][kh] = LDSB(r, kh);
        }
        #pragma unroll
        for (int rf = 0; rf < 4; ++rf) {
            const int r = arow16 + rf*16;
            #pragma unroll
            for (int kh = 0; kh < 2; ++kh) a[rf][kh] = LDSA(r, kh);
        }
        asm volatile("s_barrier" ::: "memory");
        __builtin_amdgcn_sched_barrier(0);
        __builtin_amdgcn_s_setprio(1);
        #pragma unroll
        for (int kh = 0; kh < 2; ++kh)
            #pragma unroll
            for (int rf = 0; rf < 4; ++rf)
                #pragma unroll
                for (int cf = 0; cf < 2; ++cf)
                    acc[rf][cf] = __builtin_amdgcn_mfma_f32_16x16x32_bf16(a[rf][kh], b0[cf][kh], acc[rf][cf], 0, 0, 0);
        __builtin_amdgcn_s_setprio(0);

        // ---- ph1: q0 x c1 ----
        #pragma unroll
        for (int cf = 0; cf < 2; ++cf) {
            const int r = brow16 + 32 + cf*16;
            #pragma unroll
            for (int kh = 0; kh < 2; ++kh) b1[cf][kh] = LDSB(r, kh);
        }
        asm volatile("s_barrier" ::: "memory");
        __builtin_amdgcn_sched_barrier(0);
        __builtin_amdgcn_s_setprio(1);
        #pragma unroll
        for (int kh = 0; kh < 2; ++kh)
            #pragma unroll
            for (int rf = 0; rf < 4; ++rf)
                #pragma unroll
                for (int cf = 0; cf < 2; ++cf)
                    acc[rf][2+cf] = __builtin_amdgcn_mfma_f32_16x16x32_bf16(a[rf][kh], b1[cf][kh], acc[rf][2+cf], 0, 0, 0);
        __builtin_amdgcn_s_setprio(0);

        // ---- ph2: q1 x c0 ----
        if (s + 2 < NK) stageB(s + 2, 0);
        #pragma unroll
        for (int rf = 0; rf < 4; ++rf) {
            const int r = arow16 + 64 + rf*16;
            #pragma unroll
            for (int kh = 0; kh < 2; ++kh) a[rf][kh] = LDSA(r, kh);
        }
        asm volatile("s_barrier" ::: "memory");
        __builtin_amdgcn_sched_barrier(0);
        __builtin_amdgcn_s_setprio(1);
        #pragma unroll
        for (int kh = 0; kh < 2; ++kh)
            #pragma unroll
            for (int rf = 0; rf < 4; ++rf)
                #pragma unroll
                for (int cf = 0; cf < 2; ++cf)
                    acc[4+rf][cf] = __builtin_amdgcn_mfma_f32_16x16x32_bf16(a[rf][kh], b0[cf][kh], acc[4+rf][cf], 0, 0, 0);
        __builtin_amdgcn_s_setprio(0);

        // ---- ph3: q1 x c1 ----
        if (s + 2 < NK) stageB(s + 2, 1);
        if (s + 1 < NK) {
            if (s + 2 < NK) asm volatile("s_waitcnt vmcnt(8)" ::: "memory");
            else            asm volatile("s_waitcnt vmcnt(0)" ::: "memory");
            asm volatile("s_barrier" ::: "memory");
            __builtin_amdgcn_sched_barrier(0);
        }
        __builtin_amdgcn_s_setprio(1);
        #pragma unroll
        for (int kh = 0; kh < 2; ++kh)
            #pragma unroll
            for (int rf = 0; rf < 4; ++rf)
                #pragma unroll
                for (int cf = 0; cf < 2; ++cf)
                    acc[4+rf][2+cf] = __builtin_amdgcn_mfma_f32_16x16x32_bf16(a[rf][kh], b1[cf][kh], acc[4+rf][2+cf], 0, 0, 0);
        __builtin_amdgcn_s_setprio(0);
    }
    #undef LDSA
    #undef LDSB

    // C/D layout: col = lane&15, row = (lane>>4)*4 + reg  [m89/m91]
    const long crow0 = rowA0 + wm*128 + ((lane >> 4) * 4);
    const int  ccol0 = (int)rowB0 + wn*64 + (lane & 15);
    #pragma unroll
    for (int rf = 0; rf < 8; ++rf) {
        #pragma unroll
        for (int cf = 0; cf < 4; ++cf) {
            const int col = ccol0 + cf*16;
            const float bv = be ? be[col] : 0.f;
            #pragma unroll
            for (int r = 0; r < 4; ++r) {
                const long row = crow0 + rf*16 + r;
                const float val = acc[rf][cf][r] + bv;
                if constexpr (OUT_F32) ((float*)Cout)[row*(long)ldc + col] = val;
                else ((bf16_t*)Cout)[row*(long)ldc + col] = __float2bfloat16(val);
            }
        }
    }
}

template<bool OUT_F32, bool FUSEK>
__global__ __launch_bounds__(512, 1)
void gemm256(const bf16_t* __restrict__ A, int lda, long aslab, SlabMap map, int mshift,
             const bf16_t* __restrict__ Bw, int ldb,
             const float* __restrict__ bias,
             void* __restrict__ Cout, int ldc, long cslab, int K)
{
    extern __shared__ char lds[];
    const int nwg = (int)gridDim.x;
    const int wid = (int)blockIdx.x;
    const int swz = (wid & 7) * (nwg >> 3) + (wid >> 3);
    const int bx  = swz & 7;               // N=2048 -> 8 col-blocks
    const int by  = swz >> 3;

    const int  sl    = by >> mshift;
    const long rowA0 = (long)(by & ((1 << mshift) - 1)) * 256;
    const long rowB0 = (long)bx * 256;
    const bf16_t* Ab = FUSEK ? A : (A + (long)map.a[sl] * aslab);
    const bf16_t* Wb = Bw + (long)map.w[sl] * WUNIT;
    const float*  be = bias ? (bias + (long)map.w[sl] * HH) : nullptr;
    const long cbase = (long)sl * cslab;
    void* Cj = OUT_F32 ? (void*)((float*)Cout + cbase) : (void*)((bf16_t*)Cout + cbase);
    gemm_core<OUT_F32, FUSEK>(Ab, lda, aslab, Wb, ldb, be, Cj, ldc, rowA0, rowB0, K, lds);
}

// all 18 weight-fold GEMMs (M=N=K=2048 each) in one dispatch: 18 jobs x 64 blocks
__global__ __launch_bounds__(512, 1)
void gemm_fold(GJobs js)
{
    extern __shared__ char lds[];
    const int nwg = (int)gridDim.x;     // 1152, multiple of 8
    const int wid = (int)blockIdx.x;
    const int swz = (wid & 7) * (nwg >> 3) + (wid >> 3);
    const GJob jb = js.j[swz >> 6];
    const int inner = swz & 63;
    const long rowA0 = (long)(inner >> 3) * 256;
    const long rowB0 = (long)(inner & 7) * 256;
    gemm_core<false, false>(jb.A, jb.lda, 0L, jb.Bw, 2048, nullptr,
                            (void*)jb.C, jb.ldc, rowA0, rowB0, 2048, lds);
}

__global__ __launch_bounds__(256)
void f2b_kernel(const float* __restrict__ in, bf16_t* __restrict__ out, long n)
{
    long i = ((long)blockIdx.x * 256 + threadIdx.x) * 4;
    const long stride = (long)gridDim.x * 256 * 4;
    for (; i < n; i += stride) {
        const float4 v = *(const float4*)(in + i);
        __hip_bfloat162 lo, hi;
        lo.x = __float2bfloat16(v.x); lo.y = __float2bfloat16(v.y);
        hi.x = __float2bfloat16(v.z); hi.y = __float2bfloat16(v.w);
        *(__hip_bfloat162*)(out + i)     = lo;
        *(__hip_bfloat162*)(out + i + 2) = hi;
    }
}

// batched f2b over 4 equal-size [3,2048,2048] tensors
__global__ __launch_bounds__(256)
void f2b4_kernel(Ptrs4 p)
{
    const long total = 4 * WT;
    long i = ((long)blockIdx.x * 256 + threadIdx.x) * 4;
    const long stride = (long)gridDim.x * 256 * 4;
    for (; i < total; i += stride) {
        const int  t   = (int)(i / WT);
        const long off = i - (long)t * WT;
        const float4 v = *(const float4*)(p.in[t] + off);
        __hip_bfloat162 lo, hi;
        lo.x = __float2bfloat16(v.x); lo.y = __float2bfloat16(v.y);
        hi.x = __float2bfloat16(v.z); hi.y = __float2bfloat16(v.w);
        *(__hip_bfloat162*)(p.out[t] + off)     = lo;
        *(__hip_bfloat162*)(p.out[t] + off + 2) = hi;
    }
}

// batched transpose-convert: out[mat][c][r] = (bf16) in[mat][r][c], 4 tensors x 3 mats
__global__ __launch_bounds__(256)
void f2bT4_kernel(Ptrs4 p)
{
    __shared__ float sm[64][65];
    const int gmat = blockIdx.x >> 10;       // 0..11
    const int t    = gmat / 3, m = gmat % 3;
    const int tile = blockIdx.x & 1023;
    const int tr   = tile >> 5, tc = tile & 31;
    const int lr = threadIdx.x >> 4;
    const int lc = (threadIdx.x & 15) * 4;
    const float* src = p.in[t] + (long)m*WUNIT + ((long)tr*64)*2048 + tc*64;
    #pragma unroll
    for (int it = 0; it < 4; ++it) {
        const int r = lr + it*16;
        const float4 v = *(const float4*)(src + (long)r*2048 + lc);
        sm[r][lc] = v.x; sm[r][lc+1] = v.y; sm[r][lc+2] = v.z; sm[r][lc+3] = v.w;
    }
    __syncthreads();
    bf16_t* dst = p.out[t] + (long)m*WUNIT + ((long)tc*64)*2048 + tr*64;
    #pragma unroll
    for (int it = 0; it < 4; ++it) {
        const int r = lr + it*16;
        __hip_bfloat162 p0, p1;
        p0.x = __float2bfloat16(sm[lc+0][r]); p0.y = __float2bfloat16(sm[lc+1][r]);
        p1.x = __float2bfloat16(sm[lc+2][r]); p1.y = __float2bfloat16(sm[lc+3][r]);
        *(__hip_bfloat162*)(dst + (long)r*2048 + lc)     = p0;
        *(__hip_bfloat162*)(dst + (long)r*2048 + lc + 2) = p1;
    }
}

// all 16 bias folds in one dispatch: out[g2] = sum_k W2[g2*ld+k]*b1[k] + badd[g2]
__global__ __launch_bounds__(256)
void biasfold_all(FoldPack p)
{
    const FoldJob jb = p.j[blockIdx.x >> 11];
    const int g2 = blockIdx.x & 2047;
    const int t  = threadIdx.x;
    float s = 0.f;
    for (int k = t; k < jb.ld; k += 256) s += jb.W2[(long)g2*jb.ld + k] * jb.b1[k];
    #pragma unroll
    for (int off = 32; off > 0; off >>= 1) s += __shfl_xor(s, off);
    __shared__ float rs[4];
    if ((t & 63) == 0) rs[t >> 6] = s;
    __syncthreads();
    if (t == 0) jb.out[g2] = rs[0] + rs[1] + rs[2] + rs[3] + jb.badd[g2];
}

// one wave per (v, b, head): q_len=1 attention over the 2 other views.
__global__ __launch_bounds__(256)
void attn_kernel(const bf16_t* __restrict__ q2, const bf16_t* __restrict__ k2,
                 const bf16_t* __restrict__ v2, bf16_t* __restrict__ ctx, int bshift)
{
    const long gw = (long)blockIdx.x * 4 + (threadIdx.x >> 6);
    const int lane = threadIdx.x & 63;
    const int  v_  = (int)(gw >> (bshift + 4));
    const long rem = gw & ((1L << (bshift + 4)) - 1);
    const long b   = rem >> 4;
    const int  n   = (int)(rem & 15);
    const long base = ((((long)v_ << bshift) + b)) * HH + (long)n * 128 + lane * 2;

    const __hip_bfloat162 qv = *(const __hip_bfloat162*)(q2 + base);
    const float q0 = __bfloat162float(qv.x), q1 = __bfloat162float(qv.y);
    float s[2], va[2], vb[2];
    #pragma unroll
    for (int j = 0; j < 2; ++j) {
        const long kb = ((((long)(v_*2 + j) << bshift) + b)) * HH + (long)n * 128 + lane * 2;
        const __hip_bfloat162 kv = *(const __hip_bfloat162*)(k2 + kb);
        float p = q0 * __bfloat162float(kv.x) + q1 * __bfloat162float(kv.y);
        #pragma unroll
        for (int off = 32; off > 0; off >>= 1) p += __shfl_xor(p, off);
        s[j] = p;
        const __hip_bfloat162 vv = *(const __hip_bfloat162*)(v2 + kb);
        va[j] = __bfloat162float(vv.x); vb[j] = __bfloat162float(vv.y);
    }
    const float scale = 0.08838834764831845f; // 1/sqrt(128)
    const float s0 = s[0] * scale, s1 = s[1] * scale;
    const float m  = fmaxf(s0, s1);
    const float e0 = expf(s0 - m), e1 = expf(s1 - m);
    const float inv = 1.0f / (e0 + e1);
    const float a0 = e0 * inv, a1 = e1 * inv;
    __hip_bfloat162 o;
    o.x = __float2bfloat16(a0 * va[0] + a1 * va[1]);
    o.y = __float2bfloat16(a0 * vb[0] + a1 * vb[1]);
    *(__hip_bfloat162*)(ctx + base) = o;
}

// residual (views[0] chunk) + LayerNorm, one block per row
__global__ __launch_bounds__(256)
void ln_kernel(const float* __restrict__ proj, const float* __restrict__ v0,
               const float* __restrict__ gamma, const float* __restrict__ beta,
               float* __restrict__ out)
{
    const long b = blockIdx.x;
    const int t = threadIdx.x;
    const float* pr = proj + b * HH;
    const float* vw = v0 + b * HH;
    float x[8]; float s = 0.f, s2 = 0.f;
    #pragma unroll
    for (int k = 0; k < 8; ++k) {
        const int idx = t + k * 256;
        x[k] = vw[idx] + pr[idx];
        s += x[k]; s2 += x[k] * x[k];
    }
    #pragma unroll
    for (int off = 32; off > 0; off >>= 1) { s += __shfl_xor(s, off); s2 += __shfl_xor(s2, off); }
    __shared__ float rs[4], rs2[4];
    if ((t & 63) == 0) { rs[t >> 6] = s; rs2[t >> 6] = s2; }
    __syncthreads();
    s  = rs[0] + rs[1] + rs[2] + rs[3];
    s2 = rs2[0] + rs2[1] + rs2[2] + rs2[3];
    const float mu  = s * (1.0f / 2048.0f);
    const float var = s2 * (1.0f / 2048.0f) - mu * mu;
    const float rstd = rsqrtf(var + 1e-5f);
    #pragma unroll
    for (int k = 0; k < 8; ++k) {
        const int idx = t + k * 256;
        out[b * HH + idx] = (x[k] - mu) * rstd * gamma[idx] + beta[idx];
    }
}

extern "C" void kernel_launch(void* const* d_in, const int* in_sizes, int n_in,
                              void* d_out, int out_size, void* d_ws, size_t ws_size,
                              hipStream_t stream)
{
    const float* views = (const float*)d_in[0];
    const float* Wq   = (const float*)d_in[1];  const float* bq   = (const float*)d_in[2];
    const float* Wk   = (const float*)d_in[3];  const float* bk   = (const float*)d_in[4];
    const float* Wv   = (const float*)d_in[5];  const float* bv   = (const float*)d_in[6];
    const float* Wiq  = (const float*)d_in[7];  const float* biq  = (const float*)d_in[8];
    const float* Wik  = (const float*)d_in[9];  const float* bik  = (const float*)d_in[10];
    const float* Wiv  = (const float*)d_in[11]; const float* biv  = (const float*)d_in[12];
    const float* Wo   = (const float*)d_in[13]; const float* bo   = (const float*)d_in[14];
    const float* Wout = (const float*)d_in[15]; const float* bout = (const float*)d_in[16];
    const float* gamma= (const float*)d_in[17]; const float* beta = (const float*)d_in[18];

    static bool attr_set = false;
    if (!attr_set) {
        hipFuncSetAttribute((const void*)gemm256<false,false>,
                            hipFuncAttributeMaxDynamicSharedMemorySize, LDS_TOTAL);
        hipFuncSetAttribute((const void*)gemm256<true,true>,
                            hipFuncAttributeMaxDynamicSharedMemorySize, LDS_TOTAL);
        hipFuncSetAttribute((const void*)gemm_fold,
                            hipFuncAttributeMaxDynamicSharedMemorySize, LDS_TOTAL);
        attr_set = true;
    }

    // ---- workspace: persistent folded weights + overlaid {fold-scratch | activations} ----
    char* ws = (char*)d_ws;
    bf16_t* WQ2  = (bf16_t*)ws;                  // 3u folded q   (WQ2|WK2|WV2 contiguous
    bf16_t* WK2  = WQ2 + 3*WUNIT;                // 6u folded k    -> single QKV dispatch
    bf16_t* WV2  = WK2 + 6*WUNIT;                // 6u folded v    indexes WQ2 + w*WUNIT)
    bf16_t* WFIN = WV2 + 6*WUNIT;                // 3u folded final, [2048][6144]
    float*  BQ2  = (float*)(WFIN + 3*WUNIT);     // biases contiguous 3|6|6 likewise
    float*  BK2  = BQ2 + 3*HH;
    float*  BV2  = BK2 + 6*HH;
    float*  BFIN = BV2 + 6*HH;
    const long FIXED = 18L*WUNIT*2 + 16L*HH*4;   // 151,126,016 B

    char* R = ws + FIXED;
    bf16_t* WIQ   = (bf16_t*)R;
    bf16_t* WIK   = WIQ  + 3*WUNIT;
    bf16_t* WIV   = WIK  + 3*WUNIT;
    bf16_t* WOUTB = WIV  + 3*WUNIT;
    bf16_t* WQT   = WOUTB+ 3*WUNIT;
    bf16_t* WKT   = WQT  + 3*WUNIT;
    bf16_t* WVT   = WKT  + 3*WUNIT;
    bf16_t* WOT   = WVT  + 3*WUNIT;              // scratch total 24u = 201.3 MB

    const long scratch = 24L*WUNIT*2;
    long Bc = 8192;
    while (Bc > 256) {
        long need = Bc * 73728L; if (need < scratch) need = scratch;
        if (FIXED + need <= (long)ws_size) break;
        Bc >>= 1;
    }
    const int mshift = __builtin_ctzl((unsigned long)Bc) - 8;  // log2(Bc/256)
    const int bshift = __builtin_ctzl((unsigned long)Bc);      // log2(Bc)
    const long S1 = Bc * HH;

    bf16_t* VBF = (bf16_t*)R;            // views bf16 -> later ctx (3 slabs)
    bf16_t* Q2B = VBF + 3*S1;            // q2 (3)  | Q2B|K2|V2 contiguous (15 slabs)
    bf16_t* K2  = Q2B + 3*S1;            // k2 (6)
    bf16_t* V2  = K2  + 6*S1;            // v2 (6)
    float*  PROJ= (float*)K2;            // aliases K2 (dead after attn)

    // merged QKV map: slabs 0-2 q2, 3-8 k2 pairs, 9-14 v2 pairs
    const SlabMap mp15 = {{0,1,2, 1,2,0,2,0,1, 1,2,0,2,0,1},
                          {0,1,2, 3,4,5,6,7,8, 9,10,11,12,13,14}};
    const SlabMap mp1  = {{0},{0}};
    const int oth[3][2] = {{1,2},{0,2},{0,1}};

    // ---- one-time: weight conversions (2 batched dispatches) ----
    {
        Ptrs4 c1 = {{Wiq, Wik, Wiv, Wout}, {WIQ, WIK, WIV, WOUTB}};
        f2b4_kernel<<<8192, 256, 0, stream>>>(c1);
        Ptrs4 c2 = {{Wq, Wk, Wv, Wo}, {WQT, WKT, WVT, WOT}};
        f2bT4_kernel<<<12288, 256, 0, stream>>>(c2);
    }
    // ---- one-time: all 18 weight-fold GEMMs in ONE dispatch ----
    {
        GJobs js;
        for (int v = 0; v < 3; ++v)
            js.j[v] = { WIQ + (long)v*WUNIT, WQT + (long)v*WUNIT, WQ2 + (long)v*WUNIT, 2048, 2048 };
        for (int v = 0; v < 3; ++v)
            for (int j = 0; j < 2; ++j) {
                const int p = v*2 + j, o = oth[v][j];
                js.j[3 + p] = { WIK + (long)v*WUNIT, WKT + (long)o*WUNIT, WK2 + (long)p*WUNIT, 2048, 2048 };
                js.j[9 + p] = { WIV + (long)v*WUNIT, WVT + (long)o*WUNIT, WV2 + (long)p*WUNIT, 2048, 2048 };
            }
        for (int v = 0; v < 3; ++v)
            js.j[15 + v] = { WOUTB + (long)v*2048, WOT + (long)v*WUNIT, WFIN + (long)v*2048, 6144, 6144 };
        gemm_fold<<<1152, 512, LDS_TOTAL, stream>>>(js);
    }
    // ---- one-time: all 16 exact bias folds in one dispatch ----
    {
        FoldPack fp;
        for (int v = 0; v < 3; ++v)
            fp.j[v] = { Wiq + (long)v*WUNIT, bq + v*HH, biq + v*HH, BQ2 + v*HH, 2048 };
        for (int v = 0; v < 3; ++v)
            for (int j = 0; j < 2; ++j) {
                const int p = v*2 + j, o = oth[v][j];
                fp.j[3 + p] = { Wik + (long)v*WUNIT, bk + o*HH, bik + v*HH, BK2 + p*HH, 2048 };
                fp.j[9 + p] = { Wiv + (long)v*WUNIT, bv + o*HH, biv + v*HH, BV2 + p*HH, 2048 };
            }
        fp.j[15] = { Wout, bo, bout, BFIN, 6144 };
        biasfold_all<<<32768, 256, 0, stream>>>(fp);
    }

    const int nwg15 = 8 * 15 * (int)(Bc >> 8);
    const int nwg1  = 8 * 1 * (int)(Bc >> 8);
    const int vgrid = (int)((S1 / 1024 > 8192) ? 8192 : S1 / 1024);

    for (long b0 = 0; b0 < BB; b0 += Bc) {
        if (Bc == 8192) {
            f2b_kernel<<<8192, 256, 0, stream>>>(views, VBF, 3*BH);
        } else {
            for (int v = 0; v < 3; ++v)
                f2b_kernel<<<vgrid, 256, 0, stream>>>(views + v*BH + b0*HH, VBF + v*S1, S1);
        }
        // q2 + k2 + v2 in ONE 15-slab dispatch from folded weights
        gemm256<false,false><<<nwg15, 512, LDS_TOTAL, stream>>>(VBF, 2048, S1, mp15, mshift, WQ2, 2048, BQ2, (void*)Q2B, 2048, S1, 2048);
        // attention: ctx -> VBF (views_bf dead)
        attn_kernel<<<(int)(12*Bc), 256, 0, stream>>>(Q2B, K2, V2, VBF, bshift);
        // fused projection: proj = sum_v ctx[v] @ WFIN_v^T + BFIN (K=6144 over ctx slabs)
        gemm256<true,true><<<nwg1, 512, LDS_TOTAL, stream>>>(VBF, 2048, S1, mp1, mshift, WFIN, 6144, BFIN, (void*)PROJ, 2048, 0, 6144);
        // residual + LayerNorm
        ln_kernel<<<(int)Bc, 256, 0, stream>>>(PROJ, views + b0*HH, gamma, beta, ((float*)d_out) + b0*HH);
    }
}

// Round 15
// 1631.706 us; speedup vs baseline: 1.1153x; 1.0063x over previous
//
#include <hip/hip_runtime.h>
#include <hip/hip_bf16.h>

typedef __attribute__((ext_vector_type(8))) __bf16 bf16x8;
typedef __attribute__((ext_vector_type(4))) float f32x4;
typedef __hip_bfloat16 bf16_t;

#define BB 8192L
#define HH 2048L
#define BH (8192L*2048L)      // elements per full [B,H] slab
#define WUNIT (2048L*2048L)   // elements per HxH weight unit
#define WT (3L*2048L*2048L)   // elements per [3,H,H] weight tensor
#define LDS_TOTAL 163840      // A 3x32KB triple-buffer + B 2x32KB double-buffer

struct SlabMap { int a[16]; int w[16]; };
struct Ptrs4 { const float* in[4]; bf16_t* out[4]; };
struct FoldJob { const float* W2; const float* b1; const float* badd; float* out; int ld; };
struct FoldPack { FoldJob j[16]; };
struct GJob { const bf16_t* A; const bf16_t* Bw; bf16_t* C; int lda; int ldc; };
struct GJobs { GJob j[18]; };
union B8 { bf16x8 v; unsigned short u[8]; };

__device__ __forceinline__ void gload_lds16(const void* g, void* l) {
    __builtin_amdgcn_global_load_lds((__attribute__((address_space(1))) void*)g,
                                     (__attribute__((address_space(3))) void*)l, 16, 0, 0);
}

// ============ round-7 8-phase 256x256 core, 16x16x32 MFMA (measured best) ========
// per phase {stage; ds_read frags; s_barrier; sched_barrier; setprio; MFMA; setprio}.
// A triple-buffered (slot s%3), B double-buffered (slot s&1); boundary vmcnt(8)
// keeps K-tile s+2's 8 loads in flight; tail vmcnt(0). Spill-free REQUIRED
// (r10: scratch ops increment vmcnt and corrupt the hand count).
// Schedule ledger: r8 lockstep 414us / r9 2-blk 391 / r11 drift 394 /
// r13 32x32-MFMA 1060 (4-way bank conflict: 32 rows over 8 chunk slots) --
// this r7 structure is the measured local optimum (MfmaUtil ~52%).
// 16x16 frag reads conflict-free: 16 rows/lane-group over 8 XOR slots = 2-way (free, m136).
// LDS rows [*][64] bf16, XOR swizzle 16B-chunk ^= row&7, source pre-swizzled (rule 21).
template<bool OUT_F32, bool FUSEK>
__device__ __forceinline__ void gemm_core(
    const bf16_t* __restrict__ A, int lda, long aslab,
    const bf16_t* __restrict__ Wb, int ldb,
    const float* __restrict__ be,
    void* __restrict__ Cout, int ldc,
    long rowA0, long rowB0, int K, char* lds)
{
    const int tid  = threadIdx.x;
    const int lane = tid & 63;
    const int w    = tid >> 6;
    const int wm   = w >> 2, wn = w & 3;   // 2M x 4N waves

    const int srow    = tid >> 3;                       // 0..63
    const int schunk8 = ((tid & 7) ^ (srow & 7)) * 8;   // pre-swizzled src k-offset
    const int wuni    = w * 1024;                       // wave-uniform LDS base
    const int NK = K >> 6;

    auto stageA = [&](int s) {            // all 4 A quarters of K-tile s
        char* dst = lds + (s % 3) * 32768;
        const int k0 = s << 6;
        const bf16_t* Aeff; int ka;
        if constexpr (FUSEK) { Aeff = A + (long)(k0 >> 11) * aslab; ka = k0 & 2047; }
        else                 { Aeff = A; ka = k0; }
        #pragma unroll
        for (int i = 0; i < 4; ++i)
            gload_lds16(Aeff + (rowA0 + i*64 + srow) * (long)lda + (ka + schunk8), dst + i*8192 + wuni);
    };
    auto stageB = [&](int s, int q) {     // one B quarter (2 loads)
        char* dst = lds + 98304 + (s & 1) * 32768 + q*16384;
        const int k0 = s << 6;
        #pragma unroll
        for (int j = 0; j < 2; ++j)
            gload_lds16(Wb + (rowB0 + q*128 + j*64 + srow) * (long)ldb + (k0 + schunk8), dst + j*8192 + wuni);
    };

    f32x4 acc[8][4];
    const f32x4 zero = {0.f, 0.f, 0.f, 0.f};
    #pragma unroll
    for (int i = 0; i < 8; ++i)
        #pragma unroll
        for (int j = 0; j < 4; ++j) acc[i][j] = zero;

    stageA(0); stageB(0,0); stageB(0,1);
    stageA(1); stageB(1,0); stageB(1,1);
    asm volatile("s_waitcnt vmcnt(8)" ::: "memory");
    asm volatile("s_barrier" ::: "memory");

    const int arow16 = wm*128 + (lane & 15);
    const int brow16 = wn*64  + (lane & 15);
    const int kb     = (lane >> 4) * 16;

    #define LDSA(row, kh) (*(const bf16x8*)(bufA + (row)*128 + (((kh)*64 + kb) ^ (((row) & 7) << 4))))
    #define LDSB(row, kh) (*(const bf16x8*)(bufB + (row)*128 + (((kh)*64 + kb) ^ (((row) & 7) << 4))))

    for (int s = 0; s < NK; ++s) {
        char* bufA = lds + (s % 3) * 32768;
        char* bufB = lds + 98304 + (s & 1) * 32768;
        bf16x8 a[4][2], b0[2][2], b1[2][2];

        // ---- ph0: q0 x c0 ----
        if (s + 2 < NK) stageA(s + 2);
        #pragma unroll
        for (int cf = 0; cf < 2; ++cf) {
            const int r = brow16 + cf*16;
            #pragma unroll
            for (int kh = 0; kh < 2; ++kh) b0[cf][kh] = LDSB(r, kh);
        }
        #pragma unroll
        for (int rf = 0; rf < 4; ++rf) {
            const int r = arow16 + rf*16;
            #pragma unroll
            for (int kh = 0; kh < 2; ++kh) a[rf][kh] = LDSA(r, kh);
        }
        asm volatile("s_barrier" ::: "memory");
        __builtin_amdgcn_sched_barrier(0);
        __builtin_amdgcn_s_setprio(1);
        #pragma unroll
        for (int kh = 0; kh < 2; ++kh)
            #pragma unroll
            for (int rf = 0; rf < 4; ++rf)
                #pragma unroll
                for (int cf = 0; cf < 2; ++cf)
                    acc[rf][cf] = __builtin_amdgcn_mfma_f32_16x16x32_bf16(a[rf][kh], b0[cf][kh], acc[rf][cf], 0, 0, 0);
        __builtin_amdgcn_s_setprio(0);

        // ---- ph1: q0 x c1 ----
        #pragma unroll
        for (int cf = 0; cf < 2; ++cf) {
            const int r = brow16 + 32 + cf*16;
            #pragma unroll
            for (int kh = 0; kh < 2; ++kh) b1[cf][kh] = LDSB(r, kh);
        }
        asm volatile("s_barrier" ::: "memory");
        __builtin_amdgcn_sched_barrier(0);
        __builtin_amdgcn_s_setprio(1);
        #pragma unroll
        for (int kh = 0; kh < 2; ++kh)
            #pragma unroll
            for (int rf = 0; rf < 4; ++rf)
                #pragma unroll
                for (int cf = 0; cf < 2; ++cf)
                    acc[rf][2+cf] = __builtin_amdgcn_mfma_f32_16x16x32_bf16(a[rf][kh], b1[cf][kh], acc[rf][2+cf], 0, 0, 0);
        __builtin_amdgcn_s_setprio(0);

        // ---- ph2: q1 x c0 ----
        if (s + 2 < NK) stageB(s + 2, 0);
        #pragma unroll
        for (int rf = 0; rf < 4; ++rf) {
            const int r = arow16 + 64 + rf*16;
            #pragma unroll
            for (int kh = 0; kh < 2; ++kh) a[rf][kh] = LDSA(r, kh);
        }
        asm volatile("s_barrier" ::: "memory");
        __builtin_amdgcn_sched_barrier(0);
        __builtin_amdgcn_s_setprio(1);
        #pragma unroll
        for (int kh = 0; kh < 2; ++kh)
            #pragma unroll
            for (int rf = 0; rf < 4; ++rf)
                #pragma unroll
                for (int cf = 0; cf < 2; ++cf)
                    acc[4+rf][cf] = __builtin_amdgcn_mfma_f32_16x16x32_bf16(a[rf][kh], b0[cf][kh], acc[4+rf][cf], 0, 0, 0);
        __builtin_amdgcn_s_setprio(0);

        // ---- ph3: q1 x c1 ----
        if (s + 2 < NK) stageB(s + 2, 1);
        if (s + 1 < NK) {
            if (s + 2 < NK) asm volatile("s_waitcnt vmcnt(8)" ::: "memory");
            else            asm volatile("s_waitcnt vmcnt(0)" ::: "memory");
            asm volatile("s_barrier" ::: "memory");
            __builtin_amdgcn_sched_barrier(0);
        }
        __builtin_amdgcn_s_setprio(1);
        #pragma unroll
        for (int kh = 0; kh < 2; ++kh)
            #pragma unroll
            for (int rf = 0; rf < 4; ++rf)
                #pragma unroll
                for (int cf = 0; cf < 2; ++cf)
                    acc[4+rf][2+cf] = __builtin_amdgcn_mfma_f32_16x16x32_bf16(a[rf][kh], b1[cf][kh], acc[4+rf][2+cf], 0, 0, 0);
        __builtin_amdgcn_s_setprio(0);
    }
    #undef LDSA
    #undef LDSB

    // C/D layout: col = lane&15, row = (lane>>4)*4 + reg  [m89/m91]
    const long crow0 = rowA0 + wm*128 + ((lane >> 4) * 4);
    const int  ccol0 = (int)rowB0 + wn*64 + (lane & 15);
    #pragma unroll
    for (int rf = 0; rf < 8; ++rf) {
        #pragma unroll
        for (int cf = 0; cf < 4; ++cf) {
            const int col = ccol0 + cf*16;
            const float bv = be ? be[col] : 0.f;
            #pragma unroll
            for (int r = 0; r < 4; ++r) {
                const long row = crow0 + rf*16 + r;
                const float val = acc[rf][cf][r] + bv;
                if constexpr (OUT_F32) ((float*)Cout)[row*(long)ldc + col] = val;
                else ((bf16_t*)Cout)[row*(long)ldc + col] = __float2bfloat16(val);
            }
        }
    }
}

template<bool OUT_F32, bool FUSEK>
__global__ __launch_bounds__(512, 1)
void gemm256(const bf16_t* __restrict__ A, int lda, long aslab, SlabMap map, int mshift,
             const bf16_t* __restrict__ Bw, int ldb,
             const float* __restrict__ bias,
             void* __restrict__ Cout, int ldc, long cslab, int K)
{
    extern __shared__ char lds[];
    const int nwg = (int)gridDim.x;
    const int wid = (int)blockIdx.x;
    const int swz = (wid & 7) * (nwg >> 3) + (wid >> 3);
    const int bx  = swz & 7;               // N=2048 -> 8 col-blocks
    const int by  = swz >> 3;

    const int  sl    = by >> mshift;
    const long rowA0 = (long)(by & ((1 << mshift) - 1)) * 256;
    const long rowB0 = (long)bx * 256;
    const bf16_t* Ab = FUSEK ? A : (A + (long)map.a[sl] * aslab);
    const bf16_t* Wb = Bw + (long)map.w[sl] * WUNIT;
    const float*  be = bias ? (bias + (long)map.w[sl] * HH) : nullptr;
    const long cbase = (long)sl * cslab;
    void* Cj = OUT_F32 ? (void*)((float*)Cout + cbase) : (void*)((bf16_t*)Cout + cbase);
    gemm_core<OUT_F32, FUSEK>(Ab, lda, aslab, Wb, ldb, be, Cj, ldc, rowA0, rowB0, K, lds);
}

// all 18 weight-fold GEMMs (M=N=K=2048 each) in one dispatch: 18 jobs x 64 blocks
__global__ __launch_bounds__(512, 1)
void gemm_fold(GJobs js)
{
    extern __shared__ char lds[];
    const int nwg = (int)gridDim.x;     // 1152, multiple of 8
    const int wid = (int)blockIdx.x;
    const int swz = (wid & 7) * (nwg >> 3) + (wid >> 3);
    const GJob jb = js.j[swz >> 6];
    const int inner = swz & 63;
    const long rowA0 = (long)(inner >> 3) * 256;
    const long rowB0 = (long)(inner & 7) * 256;
    gemm_core<false, false>(jb.A, jb.lda, 0L, jb.Bw, 2048, nullptr,
                            (void*)jb.C, jb.ldc, rowA0, rowB0, 2048, lds);
}

__global__ __launch_bounds__(256)
void f2b_kernel(const float* __restrict__ in, bf16_t* __restrict__ out, long n)
{
    long i = ((long)blockIdx.x * 256 + threadIdx.x) * 4;
    const long stride = (long)gridDim.x * 256 * 4;
    for (; i < n; i += stride) {
        const float4 v = *(const float4*)(in + i);
        __hip_bfloat162 lo, hi;
        lo.x = __float2bfloat16(v.x); lo.y = __float2bfloat16(v.y);
        hi.x = __float2bfloat16(v.z); hi.y = __float2bfloat16(v.w);
        *(__hip_bfloat162*)(out + i)     = lo;
        *(__hip_bfloat162*)(out + i + 2) = hi;
    }
}

// batched f2b over 4 equal-size [3,2048,2048] tensors
__global__ __launch_bounds__(256)
void f2b4_kernel(Ptrs4 p)
{
    const long total = 4 * WT;
    long i = ((long)blockIdx.x * 256 + threadIdx.x) * 4;
    const long stride = (long)gridDim.x * 256 * 4;
    for (; i < total; i += stride) {
        const int  t   = (int)(i / WT);
        const long off = i - (long)t * WT;
        const float4 v = *(const float4*)(p.in[t] + off);
        __hip_bfloat162 lo, hi;
        lo.x = __float2bfloat16(v.x); lo.y = __float2bfloat16(v.y);
        hi.x = __float2bfloat16(v.z); hi.y = __float2bfloat16(v.w);
        *(__hip_bfloat162*)(p.out[t] + off)     = lo;
        *(__hip_bfloat162*)(p.out[t] + off + 2) = hi;
    }
}

// batched transpose-convert: out[mat][c][r] = (bf16) in[mat][r][c], 4 tensors x 3 mats
__global__ __launch_bounds__(256)
void f2bT4_kernel(Ptrs4 p)
{
    __shared__ float sm[64][65];
    const int gmat = blockIdx.x >> 10;       // 0..11
    const int t    = gmat / 3, m = gmat % 3;
    const int tile = blockIdx.x & 1023;
    const int tr   = tile >> 5, tc = tile & 31;
    const int lr = threadIdx.x >> 4;
    const int lc = (threadIdx.x & 15) * 4;
    const float* src = p.in[t] + (long)m*WUNIT + ((long)tr*64)*2048 + tc*64;
    #pragma unroll
    for (int it = 0; it < 4; ++it) {
        const int r = lr + it*16;
        const float4 v = *(const float4*)(src + (long)r*2048 + lc);
        sm[r][lc] = v.x; sm[r][lc+1] = v.y; sm[r][lc+2] = v.z; sm[r][lc+3] = v.w;
    }
    __syncthreads();
    bf16_t* dst = p.out[t] + (long)m*WUNIT + ((long)tc*64)*2048 + tr*64;
    #pragma unroll
    for (int it = 0; it < 4; ++it) {
        const int r = lr + it*16;
        __hip_bfloat162 p0, p1;
        p0.x = __float2bfloat16(sm[lc+0][r]); p0.y = __float2bfloat16(sm[lc+1][r]);
        p1.x = __float2bfloat16(sm[lc+2][r]); p1.y = __float2bfloat16(sm[lc+3][r]);
        *(__hip_bfloat162*)(dst + (long)r*2048 + lc)     = p0;
        *(__hip_bfloat162*)(dst + (long)r*2048 + lc + 2) = p1;
    }
}

// all 16 bias folds in one dispatch: out[g2] = sum_k W2[g2*ld+k]*b1[k] + badd[g2]
__global__ __launch_bounds__(256)
void biasfold_all(FoldPack p)
{
    const FoldJob jb = p.j[blockIdx.x >> 11];
    const int g2 = blockIdx.x & 2047;
    const int t  = threadIdx.x;
    float s = 0.f;
    for (int k = t; k < jb.ld; k += 256) s += jb.W2[(long)g2*jb.ld + k] * jb.b1[k];
    #pragma unroll
    for (int off = 32; off > 0; off >>= 1) s += __shfl_xor(s, off);
    __shared__ float rs[4];
    if ((t & 63) == 0) rs[t >> 6] = s;
    __syncthreads();
    if (t == 0) jb.out[g2] = rs[0] + rs[1] + rs[2] + rs[3] + jb.badd[g2];
}

// attention, 16B/lane: one wave = 4 heads of one (v,b); 16-lane group per head
// (16 lanes x 8 dims = 128). q_len=1, softmax over the 2 other views.
__global__ __launch_bounds__(256)
void attn_kernel(const bf16_t* __restrict__ q2, const bf16_t* __restrict__ k2,
                 const bf16_t* __restrict__ v2, bf16_t* __restrict__ ctx, int bshift)
{
    const long gw = (long)blockIdx.x * 4 + (threadIdx.x >> 6);   // 0 .. 3*Bc*4-1
    const int lane = threadIdx.x & 63;
    const int  v_  = (int)(gw >> (bshift + 2));
    const long rem = gw & ((1L << (bshift + 2)) - 1);
    const long b   = rem >> 2;
    const int  ng  = (int)(rem & 3);
    const int  sub = lane >> 4;              // head within group of 4
    const int  il  = lane & 15;              // lane within head
    const int  n   = ng*4 + sub;
    const long base = (((long)v_ << bshift) + b) * HH + (long)n * 128 + il * 8;

    B8 q8; q8.v = *(const bf16x8*)(q2 + base);
    float qf[8];
    #pragma unroll
    for (int i = 0; i < 8; ++i) qf[i] = __uint_as_float((unsigned)q8.u[i] << 16);

    float s[2], vf[2][8];
    #pragma unroll
    for (int j = 0; j < 2; ++j) {
        const long kb = (((long)(v_*2 + j) << bshift) + b) * HH + (long)n * 128 + il * 8;
        B8 k8, v8;
        k8.v = *(const bf16x8*)(k2 + kb);
        v8.v = *(const bf16x8*)(v2 + kb);
        float p = 0.f;
        #pragma unroll
        for (int i = 0; i < 8; ++i) {
            p += qf[i] * __uint_as_float((unsigned)k8.u[i] << 16);
            vf[j][i] = __uint_as_float((unsigned)v8.u[i] << 16);
        }
        #pragma unroll
        for (int off = 1; off < 16; off <<= 1) p += __shfl_xor(p, off);  // 16-lane group reduce
        s[j] = p;
    }
    const float scale = 0.08838834764831845f; // 1/sqrt(128)
    const float s0 = s[0] * scale, s1 = s[1] * scale;
    const float m  = fmaxf(s0, s1);
    const float e0 = expf(s0 - m), e1 = expf(s1 - m);
    const float inv = 1.0f / (e0 + e1);
    const float a0 = e0 * inv, a1 = e1 * inv;
    B8 o8;
    #pragma unroll
    for (int i = 0; i < 8; ++i) {
        const bf16_t ob = __float2bfloat16(a0 * vf[0][i] + a1 * vf[1][i]);
        o8.u[i] = *(const unsigned short*)&ob;
    }
    *(bf16x8*)(ctx + base) = o8.v;
}

// residual (views[0]) + LayerNorm, one block per row, float4 loads/stores (G13)
__global__ __launch_bounds__(256)
void ln_kernel(const float* __restrict__ proj, const float* __restrict__ v0,
               const float* __restrict__ gamma, const float* __restrict__ beta,
               float* __restrict__ out)
{
    const long b = blockIdx.x;
    const int t = threadIdx.x;
    const float4* pr = (const float4*)(proj + b * HH);
    const float4* vw = (const float4*)(v0 + b * HH);
    float4 x[2]; float s = 0.f, s2 = 0.f;
    #pragma unroll
    for (int k = 0; k < 2; ++k) {
        const int idx = t + k * 256;     // 512 float4 = 2048 floats
        const float4 a = vw[idx];
        const float4 c = pr[idx];
        float4 xv = {a.x + c.x, a.y + c.y, a.z + c.z, a.w + c.w};
        x[k] = xv;
        s  += xv.x + xv.y + xv.z + xv.w;
        s2 += xv.x*xv.x + xv.y*xv.y + xv.z*xv.z + xv.w*xv.w;
    }
    #pragma unroll
    for (int off = 32; off > 0; off >>= 1) { s += __shfl_xor(s, off); s2 += __shfl_xor(s2, off); }
    __shared__ float rs[4], rs2[4];
    if ((t & 63) == 0) { rs[t >> 6] = s; rs2[t >> 6] = s2; }
    __syncthreads();
    s  = rs[0] + rs[1] + rs[2] + rs[3];
    s2 = rs2[0] + rs2[1] + rs2[2] + rs2[3];
    const float mu  = s * (1.0f / 2048.0f);
    const float var = s2 * (1.0f / 2048.0f) - mu * mu;
    const float rstd = rsqrtf(var + 1e-5f);
    float4* op = (float4*)(out + b * HH);
    #pragma unroll
    for (int k = 0; k < 2; ++k) {
        const int idx = t + k * 256;
        const float4 g  = ((const float4*)gamma)[idx];
        const float4 bt = ((const float4*)beta)[idx];
        float4 o;
        o.x = (x[k].x - mu) * rstd * g.x + bt.x;
        o.y = (x[k].y - mu) * rstd * g.y + bt.y;
        o.z = (x[k].z - mu) * rstd * g.z + bt.z;
        o.w = (x[k].w - mu) * rstd * g.w + bt.w;
        op[idx] = o;
    }
}

extern "C" void kernel_launch(void* const* d_in, const int* in_sizes, int n_in,
                              void* d_out, int out_size, void* d_ws, size_t ws_size,
                              hipStream_t stream)
{
    const float* views = (const float*)d_in[0];
    const float* Wq   = (const float*)d_in[1];  const float* bq   = (const float*)d_in[2];
    const float* Wk   = (const float*)d_in[3];  const float* bk   = (const float*)d_in[4];
    const float* Wv   = (const float*)d_in[5];  const float* bv   = (const float*)d_in[6];
    const float* Wiq  = (const float*)d_in[7];  const float* biq  = (const float*)d_in[8];
    const float* Wik  = (const float*)d_in[9];  const float* bik  = (const float*)d_in[10];
    const float* Wiv  = (const float*)d_in[11]; const float* biv  = (const float*)d_in[12];
    const float* Wo   = (const float*)d_in[13]; const float* bo   = (const float*)d_in[14];
    const float* Wout = (const float*)d_in[15]; const float* bout = (const float*)d_in[16];
    const float* gamma= (const float*)d_in[17]; const float* beta = (const float*)d_in[18];

    static bool attr_set = false;
    if (!attr_set) {
        hipFuncSetAttribute((const void*)gemm256<false,false>,
                            hipFuncAttributeMaxDynamicSharedMemorySize, LDS_TOTAL);
        hipFuncSetAttribute((const void*)gemm256<true,true>,
                            hipFuncAttributeMaxDynamicSharedMemorySize, LDS_TOTAL);
        hipFuncSetAttribute((const void*)gemm_fold,
                            hipFuncAttributeMaxDynamicSharedMemorySize, LDS_TOTAL);
        attr_set = true;
    }

    // ---- workspace: persistent folded weights + overlaid {fold-scratch | activations} ----
    char* ws = (char*)d_ws;
    bf16_t* WQ2  = (bf16_t*)ws;                  // 3u folded q   (WQ2|WK2|WV2 contiguous
    bf16_t* WK2  = WQ2 + 3*WUNIT;                // 6u folded k    -> single QKV dispatch
    bf16_t* WV2  = WK2 + 6*WUNIT;                // 6u folded v    indexes WQ2 + w*WUNIT)
    bf16_t* WFIN = WV2 + 6*WUNIT;                // 3u folded final, [2048][6144]
    float*  BQ2  = (float*)(WFIN + 3*WUNIT);     // biases contiguous 3|6|6 likewise
    float*  BK2  = BQ2 + 3*HH;
    float*  BV2  = BK2 + 6*HH;
    float*  BFIN = BV2 + 6*HH;
    const long FIXED = 18L*WUNIT*2 + 16L*HH*4;   // 151,126,016 B

    char* R = ws + FIXED;
    bf16_t* WIQ   = (bf16_t*)R;
    bf16_t* WIK   = WIQ  + 3*WUNIT;
    bf16_t* WIV   = WIK  + 3*WUNIT;
    bf16_t* WOUTB = WIV  + 3*WUNIT;
    bf16_t* WQT   = WOUTB+ 3*WUNIT;
    bf16_t* WKT   = WQT  + 3*WUNIT;
    bf16_t* WVT   = WKT  + 3*WUNIT;
    bf16_t* WOT   = WVT  + 3*WUNIT;              // scratch total 24u = 201.3 MB

    const long scratch = 24L*WUNIT*2;
    long Bc = 8192;
    while (Bc > 256) {
        long need = Bc * 73728L; if (need < scratch) need = scratch;
        if (FIXED + need <= (long)ws_size) break;
        Bc >>= 1;
    }
    const int mshift = __builtin_ctzl((unsigned long)Bc) - 8;  // log2(Bc/256)
    const int bshift = __builtin_ctzl((unsigned long)Bc);      // log2(Bc)
    const long S1 = Bc * HH;

    bf16_t* VBF = (bf16_t*)R;            // views bf16 -> later ctx (3 slabs)
    bf16_t* Q2B = VBF + 3*S1;            // q2 (3)  | Q2B|K2|V2 contiguous (15 slabs)
    bf16_t* K2  = Q2B + 3*S1;            // k2 (6)
    bf16_t* V2  = K2  + 6*S1;            // v2 (6)
    float*  PROJ= (float*)K2;            // aliases K2 (dead after attn)

    // merged QKV map: slabs 0-2 q2, 3-8 k2 pairs, 9-14 v2 pairs
    const SlabMap mp15 = {{0,1,2, 1,2,0,2,0,1, 1,2,0,2,0,1},
                          {0,1,2, 3,4,5,6,7,8, 9,10,11,12,13,14}};
    const SlabMap mp1  = {{0},{0}};
    const int oth[3][2] = {{1,2},{0,2},{0,1}};

    // ---- one-time: weight conversions (2 batched dispatches) ----
    {
        Ptrs4 c1 = {{Wiq, Wik, Wiv, Wout}, {WIQ, WIK, WIV, WOUTB}};
        f2b4_kernel<<<8192, 256, 0, stream>>>(c1);
        Ptrs4 c2 = {{Wq, Wk, Wv, Wo}, {WQT, WKT, WVT, WOT}};
        f2bT4_kernel<<<12288, 256, 0, stream>>>(c2);
    }
    // ---- one-time: all 18 weight-fold GEMMs in ONE dispatch ----
    {
        GJobs js;
        for (int v = 0; v < 3; ++v)
            js.j[v] = { WIQ + (long)v*WUNIT, WQT + (long)v*WUNIT, WQ2 + (long)v*WUNIT, 2048, 2048 };
        for (int v = 0; v < 3; ++v)
            for (int j = 0; j < 2; ++j) {
                const int p = v*2 + j, o = oth[v][j];
                js.j[3 + p] = { WIK + (long)v*WUNIT, WKT + (long)o*WUNIT, WK2 + (long)p*WUNIT, 2048, 2048 };
                js.j[9 + p] = { WIV + (long)v*WUNIT, WVT + (long)o*WUNIT, WV2 + (long)p*WUNIT, 2048, 2048 };
            }
        for (int v = 0; v < 3; ++v)
            js.j[15 + v] = { WOUTB + (long)v*2048, WOT + (long)v*WUNIT, WFIN + (long)v*2048, 6144, 6144 };
        gemm_fold<<<1152, 512, LDS_TOTAL, stream>>>(js);
    }
    // ---- one-time: all 16 exact bias folds in one dispatch ----
    {
        FoldPack fp;
        for (int v = 0; v < 3; ++v)
            fp.j[v] = { Wiq + (long)v*WUNIT, bq + v*HH, biq + v*HH, BQ2 + v*HH, 2048 };
        for (int v = 0; v < 3; ++v)
            for (int j = 0; j < 2; ++j) {
                const int p = v*2 + j, o = oth[v][j];
                fp.j[3 + p] = { Wik + (long)v*WUNIT, bk + o*HH, bik + v*HH, BK2 + p*HH, 2048 };
                fp.j[9 + p] = { Wiv + (long)v*WUNIT, bv + o*HH, biv + v*HH, BV2 + p*HH, 2048 };
            }
        fp.j[15] = { Wout, bo, bout, BFIN, 6144 };
        biasfold_all<<<32768, 256, 0, stream>>>(fp);
    }

    const int nwg15 = 8 * 15 * (int)(Bc >> 8);
    const int nwg1  = 8 * 1 * (int)(Bc >> 8);
    const int vgrid = (int)((S1 / 1024 > 8192) ? 8192 : S1 / 1024);

    for (long b0 = 0; b0 < BB; b0 += Bc) {
        if (Bc == 8192) {
            f2b_kernel<<<8192, 256, 0, stream>>>(views, VBF, 3*BH);
        } else {
            for (int v = 0; v < 3; ++v)
                f2b_kernel<<<vgrid, 256, 0, stream>>>(views + v*BH + b0*HH, VBF + v*S1, S1);
        }
        // q2 + k2 + v2 in ONE 15-slab dispatch from folded weights
        gemm256<false,false><<<nwg15, 512, LDS_TOTAL, stream>>>(VBF, 2048, S1, mp15, mshift, WQ2, 2048, BQ2, (void*)Q2B, 2048, S1, 2048);
        // attention: ctx -> VBF (views_bf dead); one wave per 4 heads, 16B/lane
        attn_kernel<<<(int)(3*Bc), 256, 0, stream>>>(Q2B, K2, V2, VBF, bshift);
        // fused projection: proj = sum_v ctx[v] @ WFIN_v^T + BFIN (K=6144 over ctx slabs)
        gemm256<true,true><<<nwg1, 512, LDS_TOTAL, stream>>>(VBF, 2048, S1, mp1, mshift, WFIN, 6144, BFIN, (void*)PROJ, 2048, 0, 6144);
        // residual + LayerNorm (float4)
        ln_kernel<<<(int)Bc, 256, 0, stream>>>(PROJ, views + b0*HH, gamma, beta, ((float*)d_out) + b0*HH);
    }
}